// Round 3
// baseline (95.666 us; speedup 1.0000x reference)
//
#include <hip/hip_runtime.h>

// MaskLayer: inputs [B=512, H=14, W=14, C=512] fp32, channel-innermost.
// Key identity: rows_idx = min{h : row h contains global max M},
//               cols_idx = min{w : col w contains M}  (exact, ties included).
// So one (max, min-h, min-w) scan replaces both argmax reductions.
//
// Layout: thread = (sample b, channel-quad q, position-group grp).
//   lane&7  -> 8 quads (128 B contiguous per load instr)
//   lane>>3 -> 8 position-groups covering 25/24 of the 196 positions
//   merge via __shfl_xor(8/16/32) — intra-wave, no LDS.
// Grid: 512 samples x 4 quad-blocks = 2048 blocks x 256 threads.

typedef float f32x4 __attribute__((ext_vector_type(4)));

#define IMG  14
#define NPOS 196   // IMG*IMG
#define Q    128   // float4 quads per sample (512 ch / 4)
#define PPT  25    // positions per thread (padded; tail clamps to 195)

__global__ __launch_bounds__(256, 4)
void mask_kernel(const f32x4* __restrict__ in, f32x4* __restrict__ out) {
    const int b    = blockIdx.x >> 2;
    const int qblk = blockIdx.x & 3;
    const int lane = threadIdx.x & 63;
    const int wv   = threadIdx.x >> 6;
    const int grp  = lane >> 3;
    const int q    = qblk * 32 + wv * 8 + (lane & 7);

    // groups 0-3: 25 positions, groups 4-7: 24 (padded to 25 via clamp)
    const int start = (grp < 4) ? grp * 25 : 100 + (grp - 4) * 24;

    const f32x4* __restrict__ bin  = in  + (size_t)b * (NPOS * Q) + q;
    f32x4* __restrict__       bout = out + (size_t)b * (NPOS * Q) + q;

    const float NINF = -__builtin_inff();
    f32x4 m = {NINF, NINF, NINF, NINF};
    int hi[4] = {0, 0, 0, 0};
    int wi[4] = {0, 0, 0, 0};

    // ---- pass 1: (max, min-h, min-w) scan; independent load addresses ----
    int h = start / IMG;
    int w = start - IMG * h;
#pragma unroll
    for (int k = 0; k < PPT; ++k) {
        int p = start + k;
        bool oob = p > NPOS - 1;          // only grp==7, k==24
        int pc = oob ? NPOS - 1 : p;
        f32x4 v = bin[(size_t)pc * Q];    // addr independent of scan chain
        int hc = oob ? IMG - 1 : h;
        int wc = oob ? IMG - 1 : w;
#pragma unroll
        for (int j = 0; j < 4; ++j) {
            bool gt = v[j] > m[j];
            bool eq = v[j] == m[j];
            m[j]  = gt ? v[j] : m[j];
            hi[j] = gt ? hc : hi[j];      // h ascending in scan: eq keeps min
            int wmn = wi[j] < wc ? wi[j] : wc;
            wi[j] = gt ? wc : (eq ? wmn : wi[j]);
        }
        ++w;
        int carry = (w == IMG);
        w = carry ? 0 : w;
        h += carry;
    }

    // ---- merge the 8 position-groups: larger m wins; tie -> min h, min w ----
#pragma unroll
    for (int s = 8; s <= 32; s <<= 1) {
#pragma unroll
        for (int j = 0; j < 4; ++j) {
            float om = __shfl_xor(m[j], s, 64);
            int   oh = __shfl_xor(hi[j], s, 64);
            int   ow = __shfl_xor(wi[j], s, 64);
            if (om > m[j]) { m[j] = om; hi[j] = oh; wi[j] = ow; }
            else if (om == m[j]) {
                hi[j] = hi[j] < oh ? hi[j] : oh;
                wi[j] = wi[j] < ow ? wi[j] : ow;
            }
        }
    }

    // ---- pass 2: apply mask (reload hits L2/L3), nontemporal stores ----
    const float kk  = (float)(4.0 / 14.0);          // BETA / IMG
    const float tau = (float)(0.5 / (14.0 * 14.0)); // TAU
    h = start / IMG;
    w = start - IMG * h;
#pragma unroll
    for (int k = 0; k < PPT; ++k) {
        int p = start + k;
        bool live = p < NPOS;
        int pc = live ? p : NPOS - 1;
        f32x4 v = bin[(size_t)pc * Q];
        f32x4 o;
#pragma unroll
        for (int j = 0; j < 4; ++j) {
            int dh = h - hi[j]; dh = dh < 0 ? -dh : dh;
            int dw = w - wi[j]; dw = dw < 0 ? -dw : dw;
            float wt = fmaxf(1.0f - kk * (float)(dh + dw), -1.0f) * tau;
            o[j] = fmaxf(wt * v[j], 0.0f);
        }
        if (live) {
            __builtin_nontemporal_store(o, &bout[(size_t)pc * Q]);
        }
        ++w;
        int carry = (w == IMG);
        w = carry ? 0 : w;
        h += carry;
    }
}

extern "C" void kernel_launch(void* const* d_in, const int* in_sizes, int n_in,
                              void* d_out, int out_size, void* d_ws, size_t ws_size,
                              hipStream_t stream) {
    const f32x4* in  = (const f32x4*)d_in[0];
    f32x4*       out = (f32x4*)d_out;
    // 512 samples x 4 quad-blocks; 256 threads = 4 waves x (8 quads x 8 grps)
    mask_kernel<<<512 * 4, 256, 0, stream>>>(in, out);
}

// Round 4
// 87.227 us; speedup vs baseline: 1.0967x; 1.0967x over previous
//
#include <hip/hip_runtime.h>

// MaskLayer: inputs [B=512, H=14, W=14, C=512] fp32, channel-innermost.
// Identity: rows_idx = min{h : x[b,h,w,c] == M}, cols_idx = min{w : ... == M}
// where M = global max over (h,w). One (max, min-h, min-w) scan suffices.
//
// SINGLE-PASS: values held in registers (no pass-2 reload -> vector-memory
// path traffic drops from 3x205 MB to 2x205 MB).
// Layout: lane = pg*4 + quad; 16 position-groups (4x13 + 12x12 positions),
// 4 contiguous float4-quads (64 B segments). Merge via __shfl_xor(4/8/16/32).
// Grid: 512 samples x 8 quad-blocks = 4096 blocks x 256 threads.

typedef float f32x4 __attribute__((ext_vector_type(4)));

#define IMG  14
#define NPOS 196
#define Q    128   // float4 quads per position (512 ch / 4)

__global__ __launch_bounds__(256, 4)
void mask_kernel(const f32x4* __restrict__ in, f32x4* __restrict__ out) {
    const int b    = blockIdx.x >> 3;
    const int qblk = blockIdx.x & 7;
    const int lane = threadIdx.x & 63;
    const int wv   = threadIdx.x >> 6;
    const int pg   = lane >> 2;                       // 16 position groups
    const int q    = qblk * 16 + wv * 4 + (lane & 3); // channel quad

    const bool big   = pg < 4;                        // 13-position groups
    const int  start = big ? pg * 13 : 52 + (pg - 4) * 12;

    const f32x4* __restrict__ bin  = in  + (size_t)b * (NPOS * Q) + q;
    f32x4*       __restrict__ bout = out + (size_t)b * (NPOS * Q) + q;

    // ---- issue all loads back-to-back (independent addresses, max MLP) ----
    f32x4 v[12];
#pragma unroll
    for (int k = 0; k < 12; ++k)
        v[k] = bin[(size_t)(start + k) * Q];
    f32x4 v12;
    if (big) v12 = bin[(size_t)(start + 12) * Q];

    // ---- scan from registers: (max, min-h@max, min-w@max) per channel ----
    const int h0 = start / IMG;
    const int w0 = start - h0 * IMG;
    float m[4]; int hi[4], wi[4];
#pragma unroll
    for (int j = 0; j < 4; ++j) { m[j] = v[0][j]; hi[j] = h0; wi[j] = w0; }
    int h = h0, w = w0;
#pragma unroll
    for (int k = 1; k < 12; ++k) {
        ++w; if (w == IMG) { w = 0; ++h; }
#pragma unroll
        for (int j = 0; j < 4; ++j) {
            float x = v[k][j];
            bool gt = x > m[j];
            bool eq = x == m[j];
            m[j]  = gt ? x : m[j];
            hi[j] = gt ? h : hi[j];               // h ascending: eq keeps min
            int wmn = wi[j] < w ? wi[j] : w;
            wi[j] = gt ? w : (eq ? wmn : wi[j]);
        }
    }
    {   // 13th position (groups 0..3 only)
        int h12 = h, w12 = w;
        ++w12; if (w12 == IMG) { w12 = 0; ++h12; }
        if (big) {
#pragma unroll
            for (int j = 0; j < 4; ++j) {
                float x = v12[j];
                bool gt = x > m[j];
                bool eq = x == m[j];
                m[j]  = gt ? x : m[j];
                hi[j] = gt ? h12 : hi[j];
                int wmn = wi[j] < w12 ? wi[j] : w12;
                wi[j] = gt ? w12 : (eq ? wmn : wi[j]);
            }
        }
    }

    // ---- merge across 16 position-groups: max value; tie -> min h, min w ----
#pragma unroll
    for (int s = 4; s <= 32; s <<= 1) {
#pragma unroll
        for (int j = 0; j < 4; ++j) {
            float om = __shfl_xor(m[j], s, 64);
            int   oh = __shfl_xor(hi[j], s, 64);
            int   ow = __shfl_xor(wi[j], s, 64);
            if (om > m[j]) { m[j] = om; hi[j] = oh; wi[j] = ow; }
            else if (om == m[j]) {
                hi[j] = hi[j] < oh ? hi[j] : oh;
                wi[j] = wi[j] < ow ? wi[j] : ow;
            }
        }
    }

    // ---- pass 2: mask + store straight from registers ----
    const float kk  = (float)(4.0 / 14.0);          // BETA / IMG
    const float tau = (float)(0.5 / (14.0 * 14.0)); // TAU
    h = h0; w = w0;
#pragma unroll
    for (int k = 0; k < 12; ++k) {
        if (k) { ++w; if (w == IMG) { w = 0; ++h; } }
        f32x4 o;
#pragma unroll
        for (int j = 0; j < 4; ++j) {
            int dh = h - hi[j]; dh = dh < 0 ? -dh : dh;
            int dw = w - wi[j]; dw = dw < 0 ? -dw : dw;
            float wt = fmaxf(1.0f - kk * (float)(dh + dw), -1.0f) * tau;
            o[j] = fmaxf(wt * v[k][j], 0.0f);
        }
        __builtin_nontemporal_store(o, &bout[(size_t)(start + k) * Q]);
    }
    {
        ++w; if (w == IMG) { w = 0; ++h; }
        if (big) {
            f32x4 o;
#pragma unroll
            for (int j = 0; j < 4; ++j) {
                int dh = h - hi[j]; dh = dh < 0 ? -dh : dh;
                int dw = w - wi[j]; dw = dw < 0 ? -dw : dw;
                float wt = fmaxf(1.0f - kk * (float)(dh + dw), -1.0f) * tau;
                o[j] = fmaxf(wt * v12[j], 0.0f);
            }
            __builtin_nontemporal_store(o, &bout[(size_t)(start + 12) * Q]);
        }
    }
}

extern "C" void kernel_launch(void* const* d_in, const int* in_sizes, int n_in,
                              void* d_out, int out_size, void* d_ws, size_t ws_size,
                              hipStream_t stream) {
    const f32x4* in  = (const f32x4*)d_in[0];
    f32x4*       out = (f32x4*)d_out;
    // 512 samples x 8 quad-blocks; 256 thr = 4 waves x (16 pgs x 4 quads)
    mask_kernel<<<512 * 8, 256, 0, stream>>>(in, out);
}

// Round 5
// 76.998 us; speedup vs baseline: 1.2425x; 1.1329x over previous
//
#include <hip/hip_runtime.h>

// MaskLayer: inputs [B=512, H=14, W=14, C=512] fp32, channel-innermost.
// Identity: rows_idx = min{h : x[b,h,w,c]==M}, cols_idx = min{w : ...==M},
// M = global max over (h,w). One (max, min-h, min-w) scan replaces both
// argmaxes (exact, including jnp.argmax first-occurrence tie rules).
//
// Single-pass, register-resident. Memory shape: lane = psub*16 + q16 so each
// quarter-wave touches 16 consecutive float4-quads = 256 B = two FULL 128 B
// lines per instruction (fixes R3's 1.4x partial-line write amplification).
// 16 position-groups (4x13 + 12x12) = 4 psubs x 4 waves; merge via
// __shfl_xor(16/32) then a 2 KB LDS exchange across waves.
// Grid: 512 samples x 8 quad-blocks (16 quads each) = 4096 blocks x 256 thr.

typedef float f32x4 __attribute__((ext_vector_type(4)));

#define IMG  14
#define NPOS 196
#define Q    128   // float4 quads per position (512 ch / 4)

__global__ __launch_bounds__(256, 4)
void mask_kernel(const f32x4* __restrict__ in, f32x4* __restrict__ out) {
    const int b    = blockIdx.x >> 3;
    const int qblk = blockIdx.x & 7;
    const int lane = threadIdx.x & 63;
    const int wv   = threadIdx.x >> 6;        // wave 0..3
    const int q16  = lane & 15;               // quad within 16-quad chunk
    const int psub = lane >> 4;               // position subgroup 0..3
    const int g    = wv * 4 + psub;           // 16 position-groups
    const int q    = qblk * 16 + q16;         // channel quad

    const bool big   = g < 4;                 // 13-position groups
    const int  start = big ? g * 13 : 52 + (g - 4) * 12;

    const f32x4* __restrict__ bin  = in  + (size_t)b * (NPOS * Q) + q;
    f32x4*       __restrict__ bout = out + (size_t)b * (NPOS * Q) + q;

    // ---- issue all loads back-to-back (independent addresses) ----
    f32x4 v[12];
#pragma unroll
    for (int k = 0; k < 12; ++k)
        v[k] = bin[(size_t)(start + k) * Q];
    f32x4 v12;
    if (big) v12 = bin[(size_t)(start + 12) * Q];

    // ---- scan from registers: (max, min-h@max, min-w@max) per channel ----
    const int h0 = start / IMG;
    const int w0 = start - h0 * IMG;
    float m[4]; int hi[4], wi[4];
#pragma unroll
    for (int j = 0; j < 4; ++j) { m[j] = v[0][j]; hi[j] = h0; wi[j] = w0; }
    int h = h0, w = w0;
#pragma unroll
    for (int k = 1; k < 12; ++k) {
        ++w; if (w == IMG) { w = 0; ++h; }
#pragma unroll
        for (int j = 0; j < 4; ++j) {
            float x = v[k][j];
            bool gt = x > m[j];
            bool eq = x == m[j];
            m[j]  = gt ? x : m[j];
            hi[j] = gt ? h : hi[j];            // h ascending: eq keeps min
            int wmn = wi[j] < w ? wi[j] : w;
            wi[j] = gt ? w : (eq ? wmn : wi[j]);
        }
    }
    {   // 13th position (big groups only)
        int h12 = h, w12 = w;
        ++w12; if (w12 == IMG) { w12 = 0; ++h12; }
        if (big) {
#pragma unroll
            for (int j = 0; j < 4; ++j) {
                float x = v12[j];
                bool gt = x > m[j];
                bool eq = x == m[j];
                m[j]  = gt ? x : m[j];
                hi[j] = gt ? h12 : hi[j];
                int wmn = wi[j] < w12 ? wi[j] : w12;
                wi[j] = gt ? w12 : (eq ? wmn : wi[j]);
            }
        }
    }

    // ---- merge across 4 psubs (same q16, same wave): xor 16, 32 ----
#pragma unroll
    for (int s = 16; s <= 32; s <<= 1) {
#pragma unroll
        for (int j = 0; j < 4; ++j) {
            float om = __shfl_xor(m[j], s, 64);
            int   oh = __shfl_xor(hi[j], s, 64);
            int   ow = __shfl_xor(wi[j], s, 64);
            if (om > m[j]) { m[j] = om; hi[j] = oh; wi[j] = ow; }
            else if (om == m[j]) {
                hi[j] = hi[j] < oh ? hi[j] : oh;
                wi[j] = wi[j] < ow ? wi[j] : ow;
            }
        }
    }

    // ---- merge across the 4 waves via LDS (idempotent re-merge) ----
    __shared__ float lm[4][16][4];
    __shared__ int   lhw[4][16][4];
    if (psub == 0) {
#pragma unroll
        for (int j = 0; j < 4; ++j) {
            lm[wv][q16][j]  = m[j];
            lhw[wv][q16][j] = (hi[j] << 8) | wi[j];
        }
    }
    __syncthreads();
#pragma unroll
    for (int ov = 0; ov < 4; ++ov) {
#pragma unroll
        for (int j = 0; j < 4; ++j) {
            float om = lm[ov][q16][j];
            int   op = lhw[ov][q16][j];
            int   oh = op >> 8, ow = op & 255;
            if (om > m[j]) { m[j] = om; hi[j] = oh; wi[j] = ow; }
            else if (om == m[j]) {
                hi[j] = hi[j] < oh ? hi[j] : oh;
                wi[j] = wi[j] < ow ? wi[j] : ow;
            }
        }
    }

    // ---- pass 2: mask + store straight from registers ----
    const float kk  = (float)(4.0 / 14.0);          // BETA / IMG
    const float tau = (float)(0.5 / (14.0 * 14.0)); // TAU
    h = h0; w = w0;
#pragma unroll
    for (int k = 0; k < 12; ++k) {
        if (k) { ++w; if (w == IMG) { w = 0; ++h; } }
        f32x4 o;
#pragma unroll
        for (int j = 0; j < 4; ++j) {
            int dh = h - hi[j]; dh = dh < 0 ? -dh : dh;
            int dw = w - wi[j]; dw = dw < 0 ? -dw : dw;
            float wt = fmaxf(1.0f - kk * (float)(dh + dw), -1.0f) * tau;
            o[j] = fmaxf(wt * v[k][j], 0.0f);
        }
        __builtin_nontemporal_store(o, &bout[(size_t)(start + k) * Q]);
    }
    {
        ++w; if (w == IMG) { w = 0; ++h; }
        if (big) {
            f32x4 o;
#pragma unroll
            for (int j = 0; j < 4; ++j) {
                int dh = h - hi[j]; dh = dh < 0 ? -dh : dh;
                int dw = w - wi[j]; dw = dw < 0 ? -dw : dw;
                float wt = fmaxf(1.0f - kk * (float)(dh + dw), -1.0f) * tau;
                o[j] = fmaxf(wt * v12[j], 0.0f);
            }
            __builtin_nontemporal_store(o, &bout[(size_t)(start + 12) * Q]);
        }
    }
}

extern "C" void kernel_launch(void* const* d_in, const int* in_sizes, int n_in,
                              void* d_out, int out_size, void* d_ws, size_t ws_size,
                              hipStream_t stream) {
    const f32x4* in  = (const f32x4*)d_in[0];
    f32x4*       out = (f32x4*)d_out;
    // 512 samples x 8 quad-blocks; 256 thr = 4 waves x (4 psub x 16 quads)
    mask_kernel<<<512 * 8, 256, 0, stream>>>(in, out);
}